// Round 15
// baseline (539.689 us; speedup 1.0000x reference)
//
#include <hip/hip_runtime.h>

// TextEncoder on MI355X gfx950. fp32 globals, bf16 internals, fp32 accum MFMA.
// R22 (on R21=525.3us base; flash declared converged after R18-R21 ledger:
// occupancy 0, K/V-amortize -20, barriers -2.7, ILP 0): FFN1 GEMM retiled to
// BM=256 x BN=128 (kloop generalized via MI=BM/64). Grid 512->256 blocks
// (exactly 1 resident round at 2/CU), MFMA:stage ratio 16:8 -> 32:12
// (+78% FLOP/staged-byte), A-panel traffic halved. QKV stays 128x128 (BM=256
// would leave 64 CUs idle at N=1536); O-proj/FFN2 stay 128 (N=512 underfill).
// acc 8x v16f = 128 VGPR, ~200 total < 256 cap at (256,2).
// Kept: R21 flash (4-deep ring, 2 tiles/barrier, SW-pipelined window),
// XCD-chunked remap, Qs/Ps alias, split-K=2 gemm_sk+combine_ln, vectorized
// pack_all (Q pre-scaled SCALE*LOG2E), fused V-transpose QKV epilogue.

typedef unsigned short u16;
typedef __bf16 v8bf __attribute__((ext_vector_type(8)));
typedef float  v4f  __attribute__((ext_vector_type(4)));
typedef float  v16f __attribute__((ext_vector_type(16)));

constexpr int Bx = 4, Lx = 1024, Cx = 512, Hx = 8, Dx = 64, FCx = 2048, NLx = 4, WX = 4;
constexpr int C3 = 3 * Cx;
constexpr int BL_ = Bx * Lx;              // 4096 tokens
constexpr float SCALEx = 0.125f;
constexpr float LOG2E = 1.44269504f;
constexpr float EPSx = 1e-6f;

__device__ __forceinline__ float b2f(u16 u) {
    unsigned x = ((unsigned)u) << 16;
    return __builtin_bit_cast(float, x);
}
__device__ __forceinline__ u16 f2b(float f) {   // RNE bf16
    unsigned x = __builtin_bit_cast(unsigned, f);
    x += 0x7fffu + ((x >> 16) & 1u);
    return (u16)(x >> 16);
}
__device__ __forceinline__ float ldf(const float* p) { return *p; }
__device__ __forceinline__ float ldf(const u16* p)   { return b2f(*p); }
__device__ __forceinline__ void  stf(float* p, float v) { *p = v; }
__device__ __forceinline__ void  stf(u16* p, float v)   { *p = f2b(v); }

__device__ __forceinline__ unsigned cvt_pk_bf16(float lo, float hi) {
    unsigned r;
    asm("v_cvt_pk_bf16_f32 %0, %1, %2" : "=v"(r) : "v"(lo), "v"(hi));
    return r;
}

__device__ __forceinline__ void async16(const u16* gsrc, u16* ldst) {
    __builtin_amdgcn_global_load_lds(
        (const __attribute__((address_space(1))) unsigned int*)gsrc,
        (__attribute__((address_space(3))) unsigned int*)ldst, 16, 0, 0);
}

// XCD-chunked bijective remap: nwg must be divisible by 8 (all our grids are).
// XCD k (= lin%8 by HW round-robin) gets works [k*nwg/8, (k+1)*nwg/8).
__device__ __forceinline__ int xcd_work(int lin, int nwg) {
    return (lin & 7) * (nwg >> 3) + (lin >> 3);
}

// Stage ROWS x 64 bf16 tile into LDS (contiguous 128B rows). Physical slot s of
// row r holds GLOBAL granule s^(r&7). All lanes active, dest=base+lane*16.
template<int ROWS>
__device__ __forceinline__ void stage_sw(const u16* gbase, long rstride,
                                         u16* lds, int tid)
{
#pragma unroll
    for (int i = 0; i < ROWS * 8 / 256; i++) {
        int g = tid + i * 256;
        int r = g >> 3, s = g & 7;
        int sc = s ^ (r & 7);
        async16(gbase + (long)r * rstride + sc * 8, lds + g * 8);
    }
}
__device__ __forceinline__ int swaddr(int row, int g0) {
    return row * 64 + ((g0 ^ (row & 7)) << 3);
}

// ---- merged packing kernel, 8-wide vectorized ----
// layout: [3x1048576 qkv-w][1048576 wo][4194304 w1][4194304 w2][3x2048 qkv-b]
// Q weight/bias pre-scaled by SCALE*LOG2E so flash can use raw exp2.
__global__ __launch_bounds__(256)
void pack_all(const float* __restrict__ wq, const float* __restrict__ wk,
              const float* __restrict__ wv, const float* __restrict__ wo,
              const float* __restrict__ w1, const float* __restrict__ w2,
              const float* __restrict__ bq, const float* __restrict__ bk,
              const float* __restrict__ bv,
              u16* __restrict__ wqkvb, u16* __restrict__ wob,
              u16* __restrict__ w1b, u16* __restrict__ w2b,
              float* __restrict__ bqkvf)
{
    const int CC = Cx * Cx;                       // 262144
    const long WL = (long)C3 * Cx;                // 786432
    const int total8 = (3 * NLx * CC + NLx * CC + 2 * NLx * FCx * Cx + 3 * NLx * Cx) / 8;

    auto cvt8 = [](const float* s, u16* d, float sc) {
        float4 a = *reinterpret_cast<const float4*>(s);
        float4 b = *reinterpret_cast<const float4*>(s + 4);
        int4 o;
        u16* ou = reinterpret_cast<u16*>(&o);
        ou[0] = f2b(a.x * sc); ou[1] = f2b(a.y * sc);
        ou[2] = f2b(a.z * sc); ou[3] = f2b(a.w * sc);
        ou[4] = f2b(b.x * sc); ou[5] = f2b(b.y * sc);
        ou[6] = f2b(b.z * sc); ou[7] = f2b(b.w * sc);
        *reinterpret_cast<int4*>(d) = o;
    };

    for (int idx = blockIdx.x * 256 + threadIdx.x; idx < total8; idx += gridDim.x * 256) {
        long e = (long)idx * 8;
        if (e < 3L * NLx * CC) {                   // fused qkv weights
            int which = (int)(e >> 20);
            int rem = (int)(e & (NLx * CC - 1));
            int l = rem >> 18, o = rem & (CC - 1);
            const float* src = which == 0 ? wq : (which == 1 ? wk : wv);
            float sc = which == 0 ? SCALEx * LOG2E : 1.f;
            cvt8(src + (long)l * CC + o, wqkvb + (long)l * WL + which * CC + o, sc);
            continue;
        }
        e -= 3L * NLx * CC;
        if (e < (long)NLx * CC) { cvt8(wo + e, wob + e, 1.f); continue; }
        e -= (long)NLx * CC;
        if (e < (long)NLx * FCx * Cx) { cvt8(w1 + e, w1b + e, 1.f); continue; }
        e -= (long)NLx * FCx * Cx;
        if (e < (long)NLx * FCx * Cx) { cvt8(w2 + e, w2b + e, 1.f); continue; }
        e -= (long)NLx * FCx * Cx;
        {                                          // fused qkv bias (fp32)
            int which = (int)(e >> 11);
            int rem = (int)(e & (NLx * Cx - 1));
            int l = rem >> 9, o = rem & (Cx - 1);
            const float* src = which == 0 ? bq : (which == 1 ? bk : bv);
            float sc = which == 0 ? SCALEx * LOG2E : 1.f;
            float* dst = bqkvf + l * C3 + which * Cx + o;
#pragma unroll
            for (int j = 0; j < 8; j++) dst[j] = src[(long)l * Cx + o + j] * sc;
        }
    }
}

// ---- 32x32x16-MFMA K-loop, MI = BM/64 wave-row tiles, NI = BN/64 ----
// 4 waves in 2x2; wave tile = (BM/2) x (32*NI).
template<int BM, int BN>
__device__ __forceinline__ void kloop_3232(
    const u16* A, const u16* Bw, int K, int lda, int ldb,
    u16* As, u16* Bs, int tid, int m0, int n0, int wm, int wn,
    int l31, int half, v16f* acc)
{
    constexpr int MI = BM / 64;
    constexpr int NI = BN / 64;
    for (int k0 = 0; k0 < K; k0 += 64) {
        stage_sw<BM>(A + (long)m0 * lda + k0, lda, As, tid);
        stage_sw<BN>(Bw + (long)n0 * ldb + k0, ldb, Bs, tid);
        __syncthreads();
#pragma unroll
        for (int ks = 0; ks < 4; ks++) {
            const int g0 = ks * 2 + half;
            v8bf af[MI], bfr[NI];
#pragma unroll
            for (int mi = 0; mi < MI; mi++)
                af[mi] = *reinterpret_cast<const v8bf*>(&As[swaddr(wm + mi * 32 + l31, g0)]);
#pragma unroll
            for (int ni = 0; ni < NI; ni++)
                bfr[ni] = *reinterpret_cast<const v8bf*>(&Bs[swaddr(wn + ni * 32 + l31, g0)]);
#pragma unroll
            for (int mi = 0; mi < MI; mi++)
#pragma unroll
                for (int ni = 0; ni < NI; ni++)
                    acc[mi * NI + ni] = __builtin_amdgcn_mfma_f32_32x32x16_bf16(
                        af[mi], bfr[ni], acc[mi * NI + ni], 0, 0, 0);
        }
        __syncthreads();
    }
}

// ---- GEMM-BT (bf16 out, bias, optional relu), 32x32 MFMA ----
// vt_out != nullptr: QKV mode (BM=128,BN=128 only). Blocks with n0 >= 1024
// retile V through LDS and write vt[bh][d][l] directly (transposed).
template<int BM, int BN>
__global__ __launch_bounds__(256, 2)
void gemm_bt(const u16* __restrict__ A, const u16* __restrict__ Bw,
             u16* __restrict__ Cm, const float* __restrict__ bias,
             int K, int lda, int ldb, int ldc, int relu,
             u16* __restrict__ vt_out)
{
    constexpr int MI = BM / 64;
    constexpr int NI = BN / 64;
    __shared__ __align__(16) u16 smem[BM * 64 + BN * 64];
    u16* As = smem;
    u16* Bs = smem + BM * 64;

    const int tid = threadIdx.x;
    // XCD-chunked remap, m-major decode: each XCD owns a contiguous m-range.
    const int lin = blockIdx.y * gridDim.x + blockIdx.x;
    const int work = xcd_work(lin, gridDim.x * gridDim.y);
    const int m0 = (work / gridDim.x) * BM, n0 = (work % gridDim.x) * BN;
    const int lane = tid & 63, wid = tid >> 6;
    const int wm = (wid >> 1) * (BM / 2), wn = (wid & 1) * (32 * NI);
    const int l31 = lane & 31, half = lane >> 5;

    v16f acc[MI * NI];
#pragma unroll
    for (int t = 0; t < MI * NI; t++)
#pragma unroll
        for (int r = 0; r < 16; r++) acc[t][r] = 0.f;

    kloop_3232<BM, BN>(A, Bw, K, lda, ldb, As, Bs, tid, m0, n0, wm, wn, l31, half, acc);

    const bool vmode = (vt_out != nullptr) && (n0 >= 2 * Cx);
    if (!vmode) {
#pragma unroll
        for (int mi = 0; mi < MI; mi++)
#pragma unroll
            for (int ni = 0; ni < NI; ni++) {
                const int col = n0 + wn + ni * 32 + l31;
                const float bv = bias[col];
#pragma unroll
                for (int r = 0; r < 16; r++) {
                    const int row = m0 + wm + mi * 32 + (r & 3) + 8 * (r >> 2) + 4 * half;
                    float v = acc[mi * NI + ni][r] + bv;
                    if (relu) v = fmaxf(v, 0.f);
                    Cm[(long)row * ldc + col] = f2b(v);
                }
            }
    } else {
        // V retile: T[col][row ^ ((col&15)<<3)] (both local 0..127), 32KB = smem
        u16* T = smem;
#pragma unroll
        for (int mi = 0; mi < MI; mi++)
#pragma unroll
            for (int ni = 0; ni < NI; ni++) {
                const int lc = wn + ni * 32 + l31;
                const float bv = bias[n0 + lc];
                const int sx = (lc & 15) << 3;
#pragma unroll
                for (int r = 0; r < 16; r++) {
                    const int lr = wm + mi * 32 + (r & 3) + 8 * (r >> 2) + 4 * half;
                    T[lc * 128 + (lr ^ sx)] = f2b(acc[mi * NI + ni][r] + bv);
                }
            }
        __syncthreads();
        // transposed store: thread -> (c = tid>>1, half-row hf = tid&1)
        const int c = tid >> 1, hf = tid & 1;
        const int gc = n0 - 2 * Cx + c;          // 0..511 (global V channel)
        const int hh = gc >> 6, d = gc & 63;
        const int bb = m0 >> 10, l0 = (m0 & 1023) + hf * 64;
        u16* dst = vt_out + (((long)(bb * Hx + hh) * Dx + d) << 10) + l0;
        const int sx = (c & 15) << 3;
#pragma unroll
        for (int g = 0; g < 8; g++) {
            int4 v = *reinterpret_cast<const int4*>(&T[c * 128 + ((hf * 64 + g * 8) ^ sx)]);
            *reinterpret_cast<int4*>(dst + g * 8) = v;
        }
    }
}

// ---- split-K GEMM-BT (fp32 partials), 32x32 MFMA. N=512, M=4096. ----
template<int BM, int BN>
__global__ __launch_bounds__(256, 2)
void gemm_sk(const u16* __restrict__ A, const u16* __restrict__ Bw,
             float* __restrict__ Pp, int lda, int ldb, int kslice)
{
    __shared__ __align__(16) u16 As[BM * 64];
    __shared__ __align__(16) u16 Bs[BN * 64];

    const int tid = threadIdx.x;
    // XCD-chunked remap within the 2D part (z untouched).
    const int lin = blockIdx.y * gridDim.x + blockIdx.x;
    const int work = xcd_work(lin, gridDim.x * gridDim.y);
    const int m0 = (work / gridDim.x) * BM, n0 = (work % gridDim.x) * BN;
    const int z = blockIdx.z;
    const int lane = tid & 63, wid = tid >> 6;
    const int wm = (wid >> 1) * 64, wn = (wid & 1) * 64;
    const int l31 = lane & 31, half = lane >> 5;

    v16f acc[4];
#pragma unroll
    for (int t = 0; t < 4; t++)
#pragma unroll
        for (int r = 0; r < 16; r++) acc[t][r] = 0.f;

    kloop_3232<BM, BN>(A + z * kslice, Bw + z * kslice, kslice, lda, ldb,
                       As, Bs, tid, m0, n0, wm, wn, l31, half, acc);

    float* Pz = Pp + (long)z * BL_ * Cx;
#pragma unroll
    for (int mi = 0; mi < 2; mi++)
#pragma unroll
        for (int ni = 0; ni < 2; ni++) {
            const int col = n0 + wn + ni * 32 + l31;
#pragma unroll
            for (int r = 0; r < 16; r++) {
                const int row = m0 + wm + mi * 32 + (r & 3) + 8 * (r >> 2) + 4 * half;
                Pz[(long)row * Cx + col] = acc[mi * 2 + ni][r];
            }
        }
}

// ---- combine split-K partials + bias + residual, then LayerNorm ----
template<int SK>
__global__ __launch_bounds__(256)
void combine_ln(const float* __restrict__ Pp, const float* __restrict__ bias,
                const u16* __restrict__ res, u16* __restrict__ outp,
                const float* __restrict__ gg, const float* __restrict__ bb)
{
    const int wid = threadIdx.x >> 6, lane = threadIdx.x & 63;
    const long r = (long)blockIdx.x * 4 + wid;
    const int c0 = lane * 8;

    int4 t = *reinterpret_cast<const int4*>(res + r * Cx + c0);
    const u16* u = reinterpret_cast<const u16*>(&t);
    float x[8];
#pragma unroll
    for (int i = 0; i < 8; i++) x[i] = b2f(u[i]) + bias[c0 + i];
#pragma unroll
    for (int s = 0; s < SK; s++) {
        const float* p = Pp + ((long)s * BL_ + r) * Cx + c0;
        float4 a = *reinterpret_cast<const float4*>(p);
        float4 b = *reinterpret_cast<const float4*>(p + 4);
        x[0] += a.x; x[1] += a.y; x[2] += a.z; x[3] += a.w;
        x[4] += b.x; x[5] += b.y; x[6] += b.z; x[7] += b.w;
    }
    float s1 = 0.f, s2 = 0.f;
#pragma unroll
    for (int i = 0; i < 8; i++) { s1 += x[i]; s2 += x[i] * x[i]; }
#pragma unroll
    for (int o = 32; o > 0; o >>= 1) { s1 += __shfl_xor(s1, o, 64); s2 += __shfl_xor(s2, o, 64); }
    const float mu = s1 * (1.f / Cx);
    const float var = s2 * (1.f / Cx) - mu * mu;
    const float rs = rsqrtf(var + EPSx);
    int4 ot; u16* ou = reinterpret_cast<u16*>(&ot);
#pragma unroll
    for (int i = 0; i < 8; i++)
        ou[i] = f2b((x[i] - mu) * rs * gg[c0 + i] + bb[c0 + i]);
    *reinterpret_cast<int4*>(outp + r * Cx + c0) = ot;
}

// ---- flash attention R21 (converged): 4-deep K/V ring, 2 K-tiles per
// barrier, SW-pipelined window (QK MFMAs both tiles first). ----
__global__ __launch_bounds__(256, 2)
void flash_attn(const u16* __restrict__ qkv, const u16* __restrict__ vt,
                const float* __restrict__ relk, const float* __restrict__ relv,
                u16* __restrict__ ao)
{
    // XCD-chunked remap, bh-major: each XCD owns 4 consecutive bh (all 16
    // q-tiles) -> per-XCD K/V+Q working set ~3MB fits the 4MB private L2.
    const int lin = blockIdx.y * gridDim.x + blockIdx.x;   // bh*16 + qtile
    const int work = xcd_work(lin, 512);
    const int bh = work >> 4, b = bh >> 3, h = bh & 7;
    const int q0 = (work & 15) * 64;
    const int tid = threadIdx.x, lane = tid & 63, w = tid >> 6;
    const int lrow = lane & 15, quad = lane >> 4;
    constexpr int NT = Lx / 64;

    __shared__ __align__(16) u16 QPs[64 * 64];          // Qs (prologue) / Ps (loop)
    __shared__ __align__(16) u16 Ks[4][64 * 64];        // 4-deep ring
    __shared__ __align__(16) u16 Vs[4][64 * 64];
    __shared__ float rbias[64][9];
    __shared__ float swin[4][16][9];

    u16* Qs = QPs;
    u16* Pw = QPs + w * (16 * 64);                      // per-wave P tile

    const u16* qbase = qkv + (long)b * Lx * C3 + h * Dx;
    const u16* kbase = qbase + Cx;
    const u16* vbase = vt + (long)bh * Dx * Lx;

    stage_sw<64>(qbase + (long)q0 * C3, C3, Qs, tid);
    stage_sw<64>(kbase, C3, Ks[0], tid);
    stage_sw<64>(kbase + (long)64 * C3, C3, Ks[1], tid);
    stage_sw<64>(vbase, Lx, Vs[0], tid);
    stage_sw<64>(vbase + 64, Lx, Vs[1], tid);
    for (int i = tid; i < 4 * 16 * 9; i += 256) (&swin[0][0][0])[i] = -1e30f;
    __syncthreads();

    // Q fragments (before Qs is recycled as Ps)
    v8bf aq0 = *reinterpret_cast<const v8bf*>(&Qs[swaddr(w * 16 + lrow, quad)]);
    v8bf aq1 = *reinterpret_cast<const v8bf*>(&Qs[swaddr(w * 16 + lrow, 4 + quad)]);
    const int qw0 = q0 + w * 16;

    // rbias[r][j] = Q[q0+r] . relk[j]  (Q carries SCALE*LOG2E)
    for (int i = tid; i < 64 * 9; i += 256) {
        int r = i / 9, j = i - (i / 9) * 9;
        float d = 0.f;
#pragma unroll
        for (int g = 0; g < 8; g++) {
            v8bf qv = *reinterpret_cast<const v8bf*>(&Qs[swaddr(r, g)]);
            float4 ra = *reinterpret_cast<const float4*>(&relk[j * 64 + g * 8]);
            float4 rb = *reinterpret_cast<const float4*>(&relk[j * 64 + g * 8 + 4]);
            d += (float)qv[0] * ra.x + (float)qv[1] * ra.y
               + (float)qv[2] * ra.z + (float)qv[3] * ra.w
               + (float)qv[4] * rb.x + (float)qv[5] * rb.y
               + (float)qv[6] * rb.z + (float)qv[7] * rb.w;
        }
        rbias[r][j] = d;
    }
    __syncthreads();   // all Qs reads complete before any Ps write below

    int srow[2], scol[2];
#pragma unroll
    for (int i = 0; i < 2; i++) {
        int g = tid + i * 256;
        srow[i] = g >> 3;
        scol[i] = ((g & 7) ^ (srow[i] & 7)) * 8;
    }

    v4f out[4];
    float ls0 = 0.f, ls1 = 0.f, ls2 = 0.f, ls3 = 0.f;
#pragma unroll
    for (int nt = 0; nt < 4; nt++) out[nt] = v4f{0.f, 0.f, 0.f, 0.f};

    for (int it = 0; it < NT / 2; it++) {
        // register-prefetch tiles 2it+2 and 2it+3
        int4 pk[2][2], pv[2][2];
        if (it < NT / 2 - 1) {
#pragma unroll
            for (int j = 0; j < 2; j++) {
                const int kt2 = it * 2 + 2 + j;
                const u16* kb2 = kbase + (long)(kt2 * 64) * C3;
                const u16* vb2 = vbase + kt2 * 64;
#pragma unroll
                for (int i = 0; i < 2; i++) {
                    pk[j][i] = *reinterpret_cast<const int4*>(kb2 + (long)srow[i] * C3 + scol[i]);
                    pv[j][i] = *reinterpret_cast<const int4*>(vb2 + (long)srow[i] * Lx + scol[i]);
                }
            }
        }

        // ---- phase 1: QK MFMAs for BOTH tiles (ILP-8 covers result latency)
        v4f sfr2[2][4];
        {
            v8bf bk2[2][2][4];
#pragma unroll
            for (int s2 = 0; s2 < 2; s2++) {
                const int cur = (it * 2 + s2) & 3;
#pragma unroll
                for (int ki = 0; ki < 2; ki++)
#pragma unroll
                    for (int nt = 0; nt < 4; nt++)
                        bk2[s2][ki][nt] = *reinterpret_cast<const v8bf*>(
                            &Ks[cur][swaddr(nt * 16 + lrow, ki * 4 + quad)]);
            }
#pragma unroll
            for (int s2 = 0; s2 < 2; s2++)
#pragma unroll
                for (int nt = 0; nt < 4; nt++) sfr2[s2][nt] = v4f{0.f, 0.f, 0.f, 0.f};
            __builtin_amdgcn_s_setprio(1);
#pragma unroll
            for (int ki = 0; ki < 2; ki++)
#pragma unroll
                for (int s2 = 0; s2 < 2; s2++)
#pragma unroll
                    for (int nt = 0; nt < 4; nt++)
                        sfr2[s2][nt] = __builtin_amdgcn_mfma_f32_16x16x32_bf16(
                            bk2[s2][ki][nt], ki ? aq1 : aq0, sfr2[s2][nt], 0, 0, 0);
            __builtin_amdgcn_s_setprio(0);
        }

        // ---- phase 2: softmax + P + PV per tile
#pragma unroll
        for (int s2 = 0; s2 < 2; s2++) {
            const int kt = it * 2 + s2;
            const int k0 = kt * 64;
            const int cur = kt & 3;
            v4f* sfr = sfr2[s2];

            if (k0 <= qw0 + 15 + WX && k0 + 63 >= qw0 - WX) {
#pragma unroll
                for (int nt = 0; nt < 4; nt++) {
#pragma unroll
                    for (int r = 0; r < 4; r++) {
                        const int key = k0 + nt * 16 + quad * 4 + r;
                        const int dj = key - (qw0 + lrow);
                        if (dj >= -WX && dj <= WX) {
                            float sv = sfr[nt][r] + rbias[w * 16 + lrow][dj + WX];
                            sfr[nt][r] = sv;
                            swin[w][lrow][dj + WX] = sv;
                        }
                    }
                }
            }

            // scores carry log2e -> raw exp2
#pragma unroll
            for (int nt = 0; nt < 4; nt++) {
                float p0 = __builtin_amdgcn_exp2f(sfr[nt][0]);
                float p1 = __builtin_amdgcn_exp2f(sfr[nt][1]);
                float p2 = __builtin_amdgcn_exp2f(sfr[nt][2]);
                float p3 = __builtin_amdgcn_exp2f(sfr[nt][3]);
                sfr[nt][0] = p0; sfr[nt][1] = p1; sfr[nt][2] = p2; sfr[nt][3] = p3;
                ls0 += p0; ls1 += p1; ls2 += p2; ls3 += p3;
            }

            // packed P write: row = q (lrow), col = key-in-tile, swizzled
#pragma unroll
            for (int nt = 0; nt < 4; nt++) {
                const int g0 = nt * 2 + (quad >> 1);
                const int base = lrow * 64 + ((g0 ^ (lrow & 7)) << 3) + (quad & 1) * 4;
#pragma unroll
                for (int j = 0; j < 2; j++) {
                    unsigned pku = cvt_pk_bf16(sfr[nt][2 * j], sfr[nt][2 * j + 1]);
                    *reinterpret_cast<unsigned*>(&Pw[base + 2 * j]) = pku;
                }
            }

            v8bf bv2[2][4];
#pragma unroll
            for (int ki = 0; ki < 2; ki++)
#pragma unroll
                for (int nt = 0; nt < 4; nt++)
                    bv2[ki][nt] = *reinterpret_cast<const v8bf*>(
                        &Vs[cur][swaddr(nt * 16 + lrow, ki * 4 + quad)]);

            v8bf pa0 = *reinterpret_cast<const v8bf*>(&Pw[swaddr(lrow, quad)]);
            v8bf pa1 = *reinterpret_cast<const v8bf*>(&Pw[swaddr(lrow, 4 + quad)]);
            __builtin_amdgcn_s_setprio(1);
#pragma unroll
            for (int nt = 0; nt < 4; nt++) {
                out[nt] = __builtin_amdgcn_mfma_f32_16x16x32_bf16(pa0, bv2[0][nt], out[nt], 0, 0, 0);
                out[nt] = __builtin_amdgcn_mfma_f32_16x16x32_bf16(pa1, bv2[1][nt], out[nt], 0, 0, 0);
            }
            __builtin_amdgcn_s_setprio(0);
        }

        // write prefetched tiles into the DISJOINT ring slot pair, then one
        // barrier (WAR on the pair just read is protected by this barrier).
        if (it < NT / 2 - 1) {
#pragma unroll
            for (int j = 0; j < 2; j++) {
                const int slot = (it * 2 + 2 + j) & 3;
                u16* Kn = Ks[slot];
                u16* Vn = Vs[slot];
#pragma unroll
                for (int i = 0; i < 2; i++) {
                    *reinterpret_cast<int4*>(Kn + (tid + i * 256) * 8) = pk[j][i];
                    *reinterpret_cast<int4*>(Vn + (tid + i * 256) * 8) = pv[j][i];
                }
            }
        }
        __syncthreads();
    }

    float lsum = (ls0 + ls1) + (ls2 + ls3);
    lsum += __shfl_xor(lsum, 16, 64);
    lsum += __shfl_xor(lsum, 32, 64);
    float inv[4];
#pragma unroll
    for (int r = 0; r < 4; r++) inv[r] = 1.f / __shfl(lsum, quad * 4 + r, 64);

    float e[4][9];
#pragma unroll
    for (int r = 0; r < 4; r++)
#pragma unroll
        for (int j = 0; j < 9; j++) e[r][j] = __builtin_amdgcn_exp2f(swin[w][quad * 4 + r][j]);
#pragma unroll
    for (int nt = 0; nt < 4; nt++) {
        const int d = nt * 16 + lrow;
#pragma unroll
        for (int r = 0; r < 4; r++) {
            float a = out[nt][r];
#pragma unroll
            for (int j = 0; j < 9; j++) a += e[r][j] * relv[j * 64 + d];
            ao[((long)(b * Lx + qw0 + quad * 4 + r)) * Cx + h * Dx + d] = f2b(a * inv[r]);
        }
    }
}

// ---- transpose with dtype conversion ----
template<typename TI, typename TO>
__global__ __launch_bounds__(256)
void transpose_k(const TI* __restrict__ in, TO* __restrict__ outp,
                 int ld_in, int ld_out, int zdiv,
                 long si1, long si2, long so1, long so2)
{
    const int z = blockIdx.z;
    in   += (z / zdiv) * si1 + (z % zdiv) * si2;
    outp += (z / zdiv) * so1 + (z % zdiv) * so2;
    const int r0 = blockIdx.y * 32, c0 = blockIdx.x * 32;
    __shared__ float t[32][33];
    const int tid = threadIdx.x;
    const int lr = tid >> 3, lc = (tid & 7) * 4;
#pragma unroll
    for (int j = 0; j < 4; j++)
        t[lr][lc + j] = ldf(in + (long)(r0 + lr) * ld_in + (c0 + lc + j));
    __syncthreads();
#pragma unroll
    for (int j = 0; j < 4; j++)
        stf(outp + (long)(c0 + lr) * ld_out + (r0 + lc + j), t[lc + j][lr]);
}

extern "C" void kernel_launch(void* const* d_in, const int* in_sizes, int n_in,
                              void* d_out, int out_size, void* d_ws, size_t ws_size,
                              hipStream_t stream)
{
    const float* x   = (const float*)d_in[0];
    const float* wq  = (const float*)d_in[2];
    const float* bq  = (const float*)d_in[3];
    const float* wk  = (const float*)d_in[4];
    const float* bk  = (const float*)d_in[5];
    const float* wv  = (const float*)d_in[6];
    const float* bv  = (const float*)d_in[7];
    const float* wo  = (const float*)d_in[8];
    const float* bo  = (const float*)d_in[9];
    const float* rk  = (const float*)d_in[10];
    const float* rv  = (const float*)d_in[11];
    const float* l1g = (const float*)d_in[12];
    const float* l1b = (const float*)d_in[13];
    const float* w1  = (const float*)d_in[14];
    const float* b1  = (const float*)d_in[15];
    const float* w2  = (const float*)d_in[16];
    const float* b2  = (const float*)d_in[17];
    const float* l2g = (const float*)d_in[18];
    const float* l2b = (const float*)d_in[19];
    float* out = (float*)d_out;

    const long BL = (long)BL_;
    char* wp = (char*)d_ws;
    auto carveB = [&](long bytes) -> char* {
        char* p = wp;
        wp += ((bytes + 255) & ~255L);
        return p;
    };
    u16* xt    = (u16*)carveB(BL * Cx * 2);
    u16* qkv   = (u16*)carveB(BL * C3 * 2);
    u16* vt    = (u16*)carveB(BL * Cx * 2);
    u16* ao    = (u16*)carveB(BL * Cx * 2);
    u16* x2    = (u16*)carveB(BL * Cx * 2);
    u16* h1    = (u16*)carveB(BL * FCx * 2);
    u16* wqkvb = (u16*)carveB((long)NLx * C3 * Cx * 2);
    u16* wob   = (u16*)carveB((long)NLx * Cx * Cx * 2);
    u16* w1b   = (u16*)carveB((long)NLx * FCx * Cx * 2);
    u16* w2b   = (u16*)carveB((long)NLx * Cx * FCx * 2);
    float* bqkvf = (float*)carveB((long)NLx * C3 * 4);
    float* pp    = (float*)carveB((long)2 * BL * Cx * 4);   // 16 MB split-K partials

    const int CC = Cx * Cx;
    const long WL = (long)C3 * Cx;

    pack_all<<<2048, 256, 0, stream>>>(wq, wk, wv, wo, w1, w2, bq, bk, bv,
                                       wqkvb, wob, w1b, w2b, bqkvf);

    transpose_k<float, u16><<<dim3(Lx / 32, Cx / 32, Bx), 256, 0, stream>>>(
        x, xt, Lx, Cx, 1, (long)Cx * Lx, 0, (long)Lx * Cx, 0);

    for (int i = 0; i < NLx; i++) {
        const u16* wqkvi = wqkvb + (long)i * WL;
        const u16* woi   = wob + (long)i * CC;
        const u16* w1i   = w1b + (long)i * FCx * Cx;
        const u16* w2i   = w2b + (long)i * Cx * FCx;
        const float* bqkvi = bqkvf + (long)i * C3;

        // fused QKV projection; V-tiles write vt directly (transposed epilogue)
        gemm_bt<128, 128><<<dim3(C3 / 128, BL_ / 128), 256, 0, stream>>>(
            xt, wqkvi, qkv, bqkvi, Cx, Cx, Cx, C3, 0, vt);

        flash_attn<<<dim3(Lx / 64, Bx * Hx), 256, 0, stream>>>(
            qkv, vt, rk + i * 9 * Dx, rv + i * 9 * Dx, ao);

        // O-projection: split-K=2, combine + bias + residual(xt) + LN -> x2
        gemm_sk<128, 128><<<dim3(Cx / 128, BL_ / 128, 2), 256, 0, stream>>>(
            ao, woi, pp, Cx, Cx, Cx / 2);
        combine_ln<2><<<dim3(BL_ / 4), 256, 0, stream>>>(
            pp, bo + i * Cx, xt, x2, l1g + i * Cx, l1b + i * Cx);

        // FFN1 (bias+relu): BM=256 tiles, grid 16x16 = 256 blocks (full chip)
        gemm_bt<256, 128><<<dim3(FCx / 128, BL_ / 256), 256, 0, stream>>>(
            x2, w1i, h1, b1 + i * FCx, Cx, Cx, Cx, FCx, 1, nullptr);

        // FFN2: split-K=2, combine + bias + residual(x2) + LN -> xt
        gemm_sk<128, 128><<<dim3(Cx / 128, BL_ / 128, 2), 256, 0, stream>>>(
            h1, w2i, pp, FCx, FCx, FCx / 2);
        combine_ln<2><<<dim3(BL_ / 4), 256, 0, stream>>>(
            pp, b2 + i * Cx, x2, xt, l2g + i * Cx, l2b + i * Cx);
    }

    transpose_k<u16, float><<<dim3(Cx / 32, Lx / 32, Bx), 256, 0, stream>>>(
        xt, out, Cx, Lx, 1, (long)Lx * Cx, 0, (long)Cx * Lx, 0);
}

// Round 16
// 523.076 us; speedup vs baseline: 1.0318x; 1.0318x over previous
//
#include <hip/hip_runtime.h>

// TextEncoder on MI355X gfx950. fp32 globals, bf16 internals, fp32 accum MFMA.
// R23 = exact revert to R21 (best measured 525.3us). R22's FFN1 BM=256 retile
// REVERTED (+14us: 128-VGPR accumulator pushed regalloc/scheduling into a
// worse regime; with R15's BM/BN=128x64 loss this brackets 128x128 as the
// sweet spot for this kloop). Ledger: flash converged (R18-R21: occ 0,
// amortize -20, barriers -2.7, ILP 0); GEMM tiles bracketed; split-K=2
// settled; XCD swizzle +26; LDS alias 0.
// Structure: R21 flash (4-deep K/V ring, 2 K-tiles/barrier, SW-pipelined
// window), XCD-chunked remap everywhere, Qs/Ps LDS alias, split-K=2 gemm_sk
// + combine_ln, vectorized pack_all (Q pre-scaled SCALE*LOG2E), swapped-QK^T
// + exp2 + setprio, fused V-transpose QKV epilogue, R9 32x32x16 kloop.

typedef unsigned short u16;
typedef __bf16 v8bf __attribute__((ext_vector_type(8)));
typedef float  v4f  __attribute__((ext_vector_type(4)));
typedef float  v16f __attribute__((ext_vector_type(16)));

constexpr int Bx = 4, Lx = 1024, Cx = 512, Hx = 8, Dx = 64, FCx = 2048, NLx = 4, WX = 4;
constexpr int C3 = 3 * Cx;
constexpr int BL_ = Bx * Lx;              // 4096 tokens
constexpr float SCALEx = 0.125f;
constexpr float LOG2E = 1.44269504f;
constexpr float EPSx = 1e-6f;

__device__ __forceinline__ float b2f(u16 u) {
    unsigned x = ((unsigned)u) << 16;
    return __builtin_bit_cast(float, x);
}
__device__ __forceinline__ u16 f2b(float f) {   // RNE bf16
    unsigned x = __builtin_bit_cast(unsigned, f);
    x += 0x7fffu + ((x >> 16) & 1u);
    return (u16)(x >> 16);
}
__device__ __forceinline__ float ldf(const float* p) { return *p; }
__device__ __forceinline__ float ldf(const u16* p)   { return b2f(*p); }
__device__ __forceinline__ void  stf(float* p, float v) { *p = v; }
__device__ __forceinline__ void  stf(u16* p, float v)   { *p = f2b(v); }

__device__ __forceinline__ unsigned cvt_pk_bf16(float lo, float hi) {
    unsigned r;
    asm("v_cvt_pk_bf16_f32 %0, %1, %2" : "=v"(r) : "v"(lo), "v"(hi));
    return r;
}

__device__ __forceinline__ void async16(const u16* gsrc, u16* ldst) {
    __builtin_amdgcn_global_load_lds(
        (const __attribute__((address_space(1))) unsigned int*)gsrc,
        (__attribute__((address_space(3))) unsigned int*)ldst, 16, 0, 0);
}

// XCD-chunked bijective remap: nwg must be divisible by 8 (all our grids are).
// XCD k (= lin%8 by HW round-robin) gets works [k*nwg/8, (k+1)*nwg/8).
__device__ __forceinline__ int xcd_work(int lin, int nwg) {
    return (lin & 7) * (nwg >> 3) + (lin >> 3);
}

// Stage ROWS x 64 bf16 tile into LDS (contiguous 128B rows). Physical slot s of
// row r holds GLOBAL granule s^(r&7). All lanes active, dest=base+lane*16.
template<int ROWS>
__device__ __forceinline__ void stage_sw(const u16* gbase, long rstride,
                                         u16* lds, int tid)
{
#pragma unroll
    for (int i = 0; i < ROWS * 8 / 256; i++) {
        int g = tid + i * 256;
        int r = g >> 3, s = g & 7;
        int sc = s ^ (r & 7);
        async16(gbase + (long)r * rstride + sc * 8, lds + g * 8);
    }
}
__device__ __forceinline__ int swaddr(int row, int g0) {
    return row * 64 + ((g0 ^ (row & 7)) << 3);
}

// ---- merged packing kernel, 8-wide vectorized ----
// layout: [3x1048576 qkv-w][1048576 wo][4194304 w1][4194304 w2][3x2048 qkv-b]
// Q weight/bias pre-scaled by SCALE*LOG2E so flash can use raw exp2.
__global__ __launch_bounds__(256)
void pack_all(const float* __restrict__ wq, const float* __restrict__ wk,
              const float* __restrict__ wv, const float* __restrict__ wo,
              const float* __restrict__ w1, const float* __restrict__ w2,
              const float* __restrict__ bq, const float* __restrict__ bk,
              const float* __restrict__ bv,
              u16* __restrict__ wqkvb, u16* __restrict__ wob,
              u16* __restrict__ w1b, u16* __restrict__ w2b,
              float* __restrict__ bqkvf)
{
    const int CC = Cx * Cx;                       // 262144
    const long WL = (long)C3 * Cx;                // 786432
    const int total8 = (3 * NLx * CC + NLx * CC + 2 * NLx * FCx * Cx + 3 * NLx * Cx) / 8;

    auto cvt8 = [](const float* s, u16* d, float sc) {
        float4 a = *reinterpret_cast<const float4*>(s);
        float4 b = *reinterpret_cast<const float4*>(s + 4);
        int4 o;
        u16* ou = reinterpret_cast<u16*>(&o);
        ou[0] = f2b(a.x * sc); ou[1] = f2b(a.y * sc);
        ou[2] = f2b(a.z * sc); ou[3] = f2b(a.w * sc);
        ou[4] = f2b(b.x * sc); ou[5] = f2b(b.y * sc);
        ou[6] = f2b(b.z * sc); ou[7] = f2b(b.w * sc);
        *reinterpret_cast<int4*>(d) = o;
    };

    for (int idx = blockIdx.x * 256 + threadIdx.x; idx < total8; idx += gridDim.x * 256) {
        long e = (long)idx * 8;
        if (e < 3L * NLx * CC) {                   // fused qkv weights
            int which = (int)(e >> 20);
            int rem = (int)(e & (NLx * CC - 1));
            int l = rem >> 18, o = rem & (CC - 1);
            const float* src = which == 0 ? wq : (which == 1 ? wk : wv);
            float sc = which == 0 ? SCALEx * LOG2E : 1.f;
            cvt8(src + (long)l * CC + o, wqkvb + (long)l * WL + which * CC + o, sc);
            continue;
        }
        e -= 3L * NLx * CC;
        if (e < (long)NLx * CC) { cvt8(wo + e, wob + e, 1.f); continue; }
        e -= (long)NLx * CC;
        if (e < (long)NLx * FCx * Cx) { cvt8(w1 + e, w1b + e, 1.f); continue; }
        e -= (long)NLx * FCx * Cx;
        if (e < (long)NLx * FCx * Cx) { cvt8(w2 + e, w2b + e, 1.f); continue; }
        e -= (long)NLx * FCx * Cx;
        {                                          // fused qkv bias (fp32)
            int which = (int)(e >> 11);
            int rem = (int)(e & (NLx * Cx - 1));
            int l = rem >> 9, o = rem & (Cx - 1);
            const float* src = which == 0 ? bq : (which == 1 ? bk : bv);
            float sc = which == 0 ? SCALEx * LOG2E : 1.f;
            float* dst = bqkvf + l * C3 + which * Cx + o;
#pragma unroll
            for (int j = 0; j < 8; j++) dst[j] = src[(long)l * Cx + o + j] * sc;
        }
    }
}

// ---- 32x32x16-MFMA K-loop, NI = BN/64 wave-col tiles ----
template<int BM, int BN>
__device__ __forceinline__ void kloop_3232(
    const u16* A, const u16* Bw, int K, int lda, int ldb,
    u16* As, u16* Bs, int tid, int m0, int n0, int wm, int wn,
    int l31, int half, v16f* acc)
{
    constexpr int NI = BN / 64;
    for (int k0 = 0; k0 < K; k0 += 64) {
        stage_sw<BM>(A + (long)m0 * lda + k0, lda, As, tid);
        stage_sw<BN>(Bw + (long)n0 * ldb + k0, ldb, Bs, tid);
        __syncthreads();
#pragma unroll
        for (int ks = 0; ks < 4; ks++) {
            const int g0 = ks * 2 + half;
            v8bf af[2], bfr[NI];
#pragma unroll
            for (int mi = 0; mi < 2; mi++)
                af[mi] = *reinterpret_cast<const v8bf*>(&As[swaddr(wm + mi * 32 + l31, g0)]);
#pragma unroll
            for (int ni = 0; ni < NI; ni++)
                bfr[ni] = *reinterpret_cast<const v8bf*>(&Bs[swaddr(wn + ni * 32 + l31, g0)]);
#pragma unroll
            for (int mi = 0; mi < 2; mi++)
#pragma unroll
                for (int ni = 0; ni < NI; ni++)
                    acc[mi * NI + ni] = __builtin_amdgcn_mfma_f32_32x32x16_bf16(
                        af[mi], bfr[ni], acc[mi * NI + ni], 0, 0, 0);
        }
        __syncthreads();
    }
}

// ---- GEMM-BT (bf16 out, bias, optional relu), 32x32 MFMA ----
// vt_out != nullptr: QKV mode (BN=128). Blocks with n0 >= 1024 retile V
// through LDS and write vt[bh][d][l] directly (transposed).
template<int BM, int BN>
__global__ __launch_bounds__(256, 2)
void gemm_bt(const u16* __restrict__ A, const u16* __restrict__ Bw,
             u16* __restrict__ Cm, const float* __restrict__ bias,
             int K, int lda, int ldb, int ldc, int relu,
             u16* __restrict__ vt_out)
{
    constexpr int NI = BN / 64;
    __shared__ __align__(16) u16 smem[BM * 64 + BN * 64];
    u16* As = smem;
    u16* Bs = smem + BM * 64;

    const int tid = threadIdx.x;
    // XCD-chunked remap, m-major decode: each XCD owns a contiguous m-range.
    const int lin = blockIdx.y * gridDim.x + blockIdx.x;
    const int work = xcd_work(lin, gridDim.x * gridDim.y);
    const int m0 = (work / gridDim.x) * BM, n0 = (work % gridDim.x) * BN;
    const int lane = tid & 63, wid = tid >> 6;
    const int wm = (wid >> 1) * 64, wn = (wid & 1) * (32 * NI);
    const int l31 = lane & 31, half = lane >> 5;

    v16f acc[2 * NI];
#pragma unroll
    for (int t = 0; t < 2 * NI; t++)
#pragma unroll
        for (int r = 0; r < 16; r++) acc[t][r] = 0.f;

    kloop_3232<BM, BN>(A, Bw, K, lda, ldb, As, Bs, tid, m0, n0, wm, wn, l31, half, acc);

    const bool vmode = (vt_out != nullptr) && (n0 >= 2 * Cx);
    if (!vmode) {
#pragma unroll
        for (int mi = 0; mi < 2; mi++)
#pragma unroll
            for (int ni = 0; ni < NI; ni++) {
                const int col = n0 + wn + ni * 32 + l31;
                const float bv = bias[col];
#pragma unroll
                for (int r = 0; r < 16; r++) {
                    const int row = m0 + wm + mi * 32 + (r & 3) + 8 * (r >> 2) + 4 * half;
                    float v = acc[mi * NI + ni][r] + bv;
                    if (relu) v = fmaxf(v, 0.f);
                    Cm[(long)row * ldc + col] = f2b(v);
                }
            }
    } else {
        // V retile: T[col][row ^ ((col&15)<<3)] (both local 0..127), 32KB = smem
        u16* T = smem;
#pragma unroll
        for (int mi = 0; mi < 2; mi++)
#pragma unroll
            for (int ni = 0; ni < NI; ni++) {
                const int lc = wn + ni * 32 + l31;
                const float bv = bias[n0 + lc];
                const int sx = (lc & 15) << 3;
#pragma unroll
                for (int r = 0; r < 16; r++) {
                    const int lr = wm + mi * 32 + (r & 3) + 8 * (r >> 2) + 4 * half;
                    T[lc * 128 + (lr ^ sx)] = f2b(acc[mi * NI + ni][r] + bv);
                }
            }
        __syncthreads();
        // transposed store: thread -> (c = tid>>1, half-row hf = tid&1)
        const int c = tid >> 1, hf = tid & 1;
        const int gc = n0 - 2 * Cx + c;          // 0..511 (global V channel)
        const int hh = gc >> 6, d = gc & 63;
        const int bb = m0 >> 10, l0 = (m0 & 1023) + hf * 64;
        u16* dst = vt_out + (((long)(bb * Hx + hh) * Dx + d) << 10) + l0;
        const int sx = (c & 15) << 3;
#pragma unroll
        for (int g = 0; g < 8; g++) {
            int4 v = *reinterpret_cast<const int4*>(&T[c * 128 + ((hf * 64 + g * 8) ^ sx)]);
            *reinterpret_cast<int4*>(dst + g * 8) = v;
        }
    }
}

// ---- split-K GEMM-BT (fp32 partials), 32x32 MFMA. N=512, M=4096. ----
template<int BM, int BN>
__global__ __launch_bounds__(256, 2)
void gemm_sk(const u16* __restrict__ A, const u16* __restrict__ Bw,
             float* __restrict__ Pp, int lda, int ldb, int kslice)
{
    __shared__ __align__(16) u16 As[BM * 64];
    __shared__ __align__(16) u16 Bs[BN * 64];

    const int tid = threadIdx.x;
    // XCD-chunked remap within the 2D part (z untouched).
    const int lin = blockIdx.y * gridDim.x + blockIdx.x;
    const int work = xcd_work(lin, gridDim.x * gridDim.y);
    const int m0 = (work / gridDim.x) * BM, n0 = (work % gridDim.x) * BN;
    const int z = blockIdx.z;
    const int lane = tid & 63, wid = tid >> 6;
    const int wm = (wid >> 1) * 64, wn = (wid & 1) * 64;
    const int l31 = lane & 31, half = lane >> 5;

    v16f acc[4];
#pragma unroll
    for (int t = 0; t < 4; t++)
#pragma unroll
        for (int r = 0; r < 16; r++) acc[t][r] = 0.f;

    kloop_3232<BM, BN>(A + z * kslice, Bw + z * kslice, kslice, lda, ldb,
                       As, Bs, tid, m0, n0, wm, wn, l31, half, acc);

    float* Pz = Pp + (long)z * BL_ * Cx;
#pragma unroll
    for (int mi = 0; mi < 2; mi++)
#pragma unroll
        for (int ni = 0; ni < 2; ni++) {
            const int col = n0 + wn + ni * 32 + l31;
#pragma unroll
            for (int r = 0; r < 16; r++) {
                const int row = m0 + wm + mi * 32 + (r & 3) + 8 * (r >> 2) + 4 * half;
                Pz[(long)row * Cx + col] = acc[mi * 2 + ni][r];
            }
        }
}

// ---- combine split-K partials + bias + residual, then LayerNorm ----
template<int SK>
__global__ __launch_bounds__(256)
void combine_ln(const float* __restrict__ Pp, const float* __restrict__ bias,
                const u16* __restrict__ res, u16* __restrict__ outp,
                const float* __restrict__ gg, const float* __restrict__ bb)
{
    const int wid = threadIdx.x >> 6, lane = threadIdx.x & 63;
    const long r = (long)blockIdx.x * 4 + wid;
    const int c0 = lane * 8;

    int4 t = *reinterpret_cast<const int4*>(res + r * Cx + c0);
    const u16* u = reinterpret_cast<const u16*>(&t);
    float x[8];
#pragma unroll
    for (int i = 0; i < 8; i++) x[i] = b2f(u[i]) + bias[c0 + i];
#pragma unroll
    for (int s = 0; s < SK; s++) {
        const float* p = Pp + ((long)s * BL_ + r) * Cx + c0;
        float4 a = *reinterpret_cast<const float4*>(p);
        float4 b = *reinterpret_cast<const float4*>(p + 4);
        x[0] += a.x; x[1] += a.y; x[2] += a.z; x[3] += a.w;
        x[4] += b.x; x[5] += b.y; x[6] += b.z; x[7] += b.w;
    }
    float s1 = 0.f, s2 = 0.f;
#pragma unroll
    for (int i = 0; i < 8; i++) { s1 += x[i]; s2 += x[i] * x[i]; }
#pragma unroll
    for (int o = 32; o > 0; o >>= 1) { s1 += __shfl_xor(s1, o, 64); s2 += __shfl_xor(s2, o, 64); }
    const float mu = s1 * (1.f / Cx);
    const float var = s2 * (1.f / Cx) - mu * mu;
    const float rs = rsqrtf(var + EPSx);
    int4 ot; u16* ou = reinterpret_cast<u16*>(&ot);
#pragma unroll
    for (int i = 0; i < 8; i++)
        ou[i] = f2b((x[i] - mu) * rs * gg[c0 + i] + bb[c0 + i]);
    *reinterpret_cast<int4*>(outp + r * Cx + c0) = ot;
}

// ---- flash attention R21 (converged): 4-deep K/V ring, 2 K-tiles per
// barrier, SW-pipelined window (QK MFMAs both tiles first). ----
__global__ __launch_bounds__(256, 2)
void flash_attn(const u16* __restrict__ qkv, const u16* __restrict__ vt,
                const float* __restrict__ relk, const float* __restrict__ relv,
                u16* __restrict__ ao)
{
    // XCD-chunked remap, bh-major: each XCD owns 4 consecutive bh (all 16
    // q-tiles) -> per-XCD K/V+Q working set ~3MB fits the 4MB private L2.
    const int lin = blockIdx.y * gridDim.x + blockIdx.x;   // bh*16 + qtile
    const int work = xcd_work(lin, 512);
    const int bh = work >> 4, b = bh >> 3, h = bh & 7;
    const int q0 = (work & 15) * 64;
    const int tid = threadIdx.x, lane = tid & 63, w = tid >> 6;
    const int lrow = lane & 15, quad = lane >> 4;
    constexpr int NT = Lx / 64;

    __shared__ __align__(16) u16 QPs[64 * 64];          // Qs (prologue) / Ps (loop)
    __shared__ __align__(16) u16 Ks[4][64 * 64];        // 4-deep ring
    __shared__ __align__(16) u16 Vs[4][64 * 64];
    __shared__ float rbias[64][9];
    __shared__ float swin[4][16][9];

    u16* Qs = QPs;
    u16* Pw = QPs + w * (16 * 64);                      // per-wave P tile

    const u16* qbase = qkv + (long)b * Lx * C3 + h * Dx;
    const u16* kbase = qbase + Cx;
    const u16* vbase = vt + (long)bh * Dx * Lx;

    stage_sw<64>(qbase + (long)q0 * C3, C3, Qs, tid);
    stage_sw<64>(kbase, C3, Ks[0], tid);
    stage_sw<64>(kbase + (long)64 * C3, C3, Ks[1], tid);
    stage_sw<64>(vbase, Lx, Vs[0], tid);
    stage_sw<64>(vbase + 64, Lx, Vs[1], tid);
    for (int i = tid; i < 4 * 16 * 9; i += 256) (&swin[0][0][0])[i] = -1e30f;
    __syncthreads();

    // Q fragments (before Qs is recycled as Ps)
    v8bf aq0 = *reinterpret_cast<const v8bf*>(&Qs[swaddr(w * 16 + lrow, quad)]);
    v8bf aq1 = *reinterpret_cast<const v8bf*>(&Qs[swaddr(w * 16 + lrow, 4 + quad)]);
    const int qw0 = q0 + w * 16;

    // rbias[r][j] = Q[q0+r] . relk[j]  (Q carries SCALE*LOG2E)
    for (int i = tid; i < 64 * 9; i += 256) {
        int r = i / 9, j = i - (i / 9) * 9;
        float d = 0.f;
#pragma unroll
        for (int g = 0; g < 8; g++) {
            v8bf qv = *reinterpret_cast<const v8bf*>(&Qs[swaddr(r, g)]);
            float4 ra = *reinterpret_cast<const float4*>(&relk[j * 64 + g * 8]);
            float4 rb = *reinterpret_cast<const float4*>(&relk[j * 64 + g * 8 + 4]);
            d += (float)qv[0] * ra.x + (float)qv[1] * ra.y
               + (float)qv[2] * ra.z + (float)qv[3] * ra.w
               + (float)qv[4] * rb.x + (float)qv[5] * rb.y
               + (float)qv[6] * rb.z + (float)qv[7] * rb.w;
        }
        rbias[r][j] = d;
    }
    __syncthreads();   // all Qs reads complete before any Ps write below

    int srow[2], scol[2];
#pragma unroll
    for (int i = 0; i < 2; i++) {
        int g = tid + i * 256;
        srow[i] = g >> 3;
        scol[i] = ((g & 7) ^ (srow[i] & 7)) * 8;
    }

    v4f out[4];
    float ls0 = 0.f, ls1 = 0.f, ls2 = 0.f, ls3 = 0.f;
#pragma unroll
    for (int nt = 0; nt < 4; nt++) out[nt] = v4f{0.f, 0.f, 0.f, 0.f};

    for (int it = 0; it < NT / 2; it++) {
        // register-prefetch tiles 2it+2 and 2it+3
        int4 pk[2][2], pv[2][2];
        if (it < NT / 2 - 1) {
#pragma unroll
            for (int j = 0; j < 2; j++) {
                const int kt2 = it * 2 + 2 + j;
                const u16* kb2 = kbase + (long)(kt2 * 64) * C3;
                const u16* vb2 = vbase + kt2 * 64;
#pragma unroll
                for (int i = 0; i < 2; i++) {
                    pk[j][i] = *reinterpret_cast<const int4*>(kb2 + (long)srow[i] * C3 + scol[i]);
                    pv[j][i] = *reinterpret_cast<const int4*>(vb2 + (long)srow[i] * Lx + scol[i]);
                }
            }
        }

        // ---- phase 1: QK MFMAs for BOTH tiles (ILP-8 covers result latency)
        v4f sfr2[2][4];
        {
            v8bf bk2[2][2][4];
#pragma unroll
            for (int s2 = 0; s2 < 2; s2++) {
                const int cur = (it * 2 + s2) & 3;
#pragma unroll
                for (int ki = 0; ki < 2; ki++)
#pragma unroll
                    for (int nt = 0; nt < 4; nt++)
                        bk2[s2][ki][nt] = *reinterpret_cast<const v8bf*>(
                            &Ks[cur][swaddr(nt * 16 + lrow, ki * 4 + quad)]);
            }
#pragma unroll
            for (int s2 = 0; s2 < 2; s2++)
#pragma unroll
                for (int nt = 0; nt < 4; nt++) sfr2[s2][nt] = v4f{0.f, 0.f, 0.f, 0.f};
            __builtin_amdgcn_s_setprio(1);
#pragma unroll
            for (int ki = 0; ki < 2; ki++)
#pragma unroll
                for (int s2 = 0; s2 < 2; s2++)
#pragma unroll
                    for (int nt = 0; nt < 4; nt++)
                        sfr2[s2][nt] = __builtin_amdgcn_mfma_f32_16x16x32_bf16(
                            bk2[s2][ki][nt], ki ? aq1 : aq0, sfr2[s2][nt], 0, 0, 0);
            __builtin_amdgcn_s_setprio(0);
        }

        // ---- phase 2: softmax + P + PV per tile
#pragma unroll
        for (int s2 = 0; s2 < 2; s2++) {
            const int kt = it * 2 + s2;
            const int k0 = kt * 64;
            const int cur = kt & 3;
            v4f* sfr = sfr2[s2];

            if (k0 <= qw0 + 15 + WX && k0 + 63 >= qw0 - WX) {
#pragma unroll
                for (int nt = 0; nt < 4; nt++) {
#pragma unroll
                    for (int r = 0; r < 4; r++) {
                        const int key = k0 + nt * 16 + quad * 4 + r;
                        const int dj = key - (qw0 + lrow);
                        if (dj >= -WX && dj <= WX) {
                            float sv = sfr[nt][r] + rbias[w * 16 + lrow][dj + WX];
                            sfr[nt][r] = sv;
                            swin[w][lrow][dj + WX] = sv;
                        }
                    }
                }
            }

            // scores carry log2e -> raw exp2
#pragma unroll
            for (int nt = 0; nt < 4; nt++) {
                float p0 = __builtin_amdgcn_exp2f(sfr[nt][0]);
                float p1 = __builtin_amdgcn_exp2f(sfr[nt][1]);
                float p2 = __builtin_amdgcn_exp2f(sfr[nt][2]);
                float p3 = __builtin_amdgcn_exp2f(sfr[nt][3]);
                sfr[nt][0] = p0; sfr[nt][1] = p1; sfr[nt][2] = p2; sfr[nt][3] = p3;
                ls0 += p0; ls1 += p1; ls2 += p2; ls3 += p3;
            }

            // packed P write: row = q (lrow), col = key-in-tile, swizzled
#pragma unroll
            for (int nt = 0; nt < 4; nt++) {
                const int g0 = nt * 2 + (quad >> 1);
                const int base = lrow * 64 + ((g0 ^ (lrow & 7)) << 3) + (quad & 1) * 4;
#pragma unroll
                for (int j = 0; j < 2; j++) {
                    unsigned pku = cvt_pk_bf16(sfr[nt][2 * j], sfr[nt][2 * j + 1]);
                    *reinterpret_cast<unsigned*>(&Pw[base + 2 * j]) = pku;
                }
            }

            v8bf bv2[2][4];
#pragma unroll
            for (int ki = 0; ki < 2; ki++)
#pragma unroll
                for (int nt = 0; nt < 4; nt++)
                    bv2[ki][nt] = *reinterpret_cast<const v8bf*>(
                        &Vs[cur][swaddr(nt * 16 + lrow, ki * 4 + quad)]);

            v8bf pa0 = *reinterpret_cast<const v8bf*>(&Pw[swaddr(lrow, quad)]);
            v8bf pa1 = *reinterpret_cast<const v8bf*>(&Pw[swaddr(lrow, 4 + quad)]);
            __builtin_amdgcn_s_setprio(1);
#pragma unroll
            for (int nt = 0; nt < 4; nt++) {
                out[nt] = __builtin_amdgcn_mfma_f32_16x16x32_bf16(pa0, bv2[0][nt], out[nt], 0, 0, 0);
                out[nt] = __builtin_amdgcn_mfma_f32_16x16x32_bf16(pa1, bv2[1][nt], out[nt], 0, 0, 0);
            }
            __builtin_amdgcn_s_setprio(0);
        }

        // write prefetched tiles into the DISJOINT ring slot pair, then one
        // barrier (WAR on the pair just read is protected by this barrier).
        if (it < NT / 2 - 1) {
#pragma unroll
            for (int j = 0; j < 2; j++) {
                const int slot = (it * 2 + 2 + j) & 3;
                u16* Kn = Ks[slot];
                u16* Vn = Vs[slot];
#pragma unroll
                for (int i = 0; i < 2; i++) {
                    *reinterpret_cast<int4*>(Kn + (tid + i * 256) * 8) = pk[j][i];
                    *reinterpret_cast<int4*>(Vn + (tid + i * 256) * 8) = pv[j][i];
                }
            }
        }
        __syncthreads();
    }

    float lsum = (ls0 + ls1) + (ls2 + ls3);
    lsum += __shfl_xor(lsum, 16, 64);
    lsum += __shfl_xor(lsum, 32, 64);
    float inv[4];
#pragma unroll
    for (int r = 0; r < 4; r++) inv[r] = 1.f / __shfl(lsum, quad * 4 + r, 64);

    float e[4][9];
#pragma unroll
    for (int r = 0; r < 4; r++)
#pragma unroll
        for (int j = 0; j < 9; j++) e[r][j] = __builtin_amdgcn_exp2f(swin[w][quad * 4 + r][j]);
#pragma unroll
    for (int nt = 0; nt < 4; nt++) {
        const int d = nt * 16 + lrow;
#pragma unroll
        for (int r = 0; r < 4; r++) {
            float a = out[nt][r];
#pragma unroll
            for (int j = 0; j < 9; j++) a += e[r][j] * relv[j * 64 + d];
            ao[((long)(b * Lx + qw0 + quad * 4 + r)) * Cx + h * Dx + d] = f2b(a * inv[r]);
        }
    }
}

// ---- transpose with dtype conversion ----
template<typename TI, typename TO>
__global__ __launch_bounds__(256)
void transpose_k(const TI* __restrict__ in, TO* __restrict__ outp,
                 int ld_in, int ld_out, int zdiv,
                 long si1, long si2, long so1, long so2)
{
    const int z = blockIdx.z;
    in   += (z / zdiv) * si1 + (z % zdiv) * si2;
    outp += (z / zdiv) * so1 + (z % zdiv) * so2;
    const int r0 = blockIdx.y * 32, c0 = blockIdx.x * 32;
    __shared__ float t[32][33];
    const int tid = threadIdx.x;
    const int lr = tid >> 3, lc = (tid & 7) * 4;
#pragma unroll
    for (int j = 0; j < 4; j++)
        t[lr][lc + j] = ldf(in + (long)(r0 + lr) * ld_in + (c0 + lc + j));
    __syncthreads();
#pragma unroll
    for (int j = 0; j < 4; j++)
        stf(outp + (long)(c0 + lr) * ld_out + (r0 + lc + j), t[lc + j][lr]);
}

extern "C" void kernel_launch(void* const* d_in, const int* in_sizes, int n_in,
                              void* d_out, int out_size, void* d_ws, size_t ws_size,
                              hipStream_t stream)
{
    const float* x   = (const float*)d_in[0];
    const float* wq  = (const float*)d_in[2];
    const float* bq  = (const float*)d_in[3];
    const float* wk  = (const float*)d_in[4];
    const float* bk  = (const float*)d_in[5];
    const float* wv  = (const float*)d_in[6];
    const float* bv  = (const float*)d_in[7];
    const float* wo  = (const float*)d_in[8];
    const float* bo  = (const float*)d_in[9];
    const float* rk  = (const float*)d_in[10];
    const float* rv  = (const float*)d_in[11];
    const float* l1g = (const float*)d_in[12];
    const float* l1b = (const float*)d_in[13];
    const float* w1  = (const float*)d_in[14];
    const float* b1  = (const float*)d_in[15];
    const float* w2  = (const float*)d_in[16];
    const float* b2  = (const float*)d_in[17];
    const float* l2g = (const float*)d_in[18];
    const float* l2b = (const float*)d_in[19];
    float* out = (float*)d_out;

    const long BL = (long)BL_;
    char* wp = (char*)d_ws;
    auto carveB = [&](long bytes) -> char* {
        char* p = wp;
        wp += ((bytes + 255) & ~255L);
        return p;
    };
    u16* xt    = (u16*)carveB(BL * Cx * 2);
    u16* qkv   = (u16*)carveB(BL * C3 * 2);
    u16* vt    = (u16*)carveB(BL * Cx * 2);
    u16* ao    = (u16*)carveB(BL * Cx * 2);
    u16* x2    = (u16*)carveB(BL * Cx * 2);
    u16* h1    = (u16*)carveB(BL * FCx * 2);
    u16* wqkvb = (u16*)carveB((long)NLx * C3 * Cx * 2);
    u16* wob   = (u16*)carveB((long)NLx * Cx * Cx * 2);
    u16* w1b   = (u16*)carveB((long)NLx * FCx * Cx * 2);
    u16* w2b   = (u16*)carveB((long)NLx * Cx * FCx * 2);
    float* bqkvf = (float*)carveB((long)NLx * C3 * 4);
    float* pp    = (float*)carveB((long)2 * BL * Cx * 4);   // 16 MB split-K partials

    const int CC = Cx * Cx;
    const long WL = (long)C3 * Cx;

    pack_all<<<2048, 256, 0, stream>>>(wq, wk, wv, wo, w1, w2, bq, bk, bv,
                                       wqkvb, wob, w1b, w2b, bqkvf);

    transpose_k<float, u16><<<dim3(Lx / 32, Cx / 32, Bx), 256, 0, stream>>>(
        x, xt, Lx, Cx, 1, (long)Cx * Lx, 0, (long)Lx * Cx, 0);

    for (int i = 0; i < NLx; i++) {
        const u16* wqkvi = wqkvb + (long)i * WL;
        const u16* woi   = wob + (long)i * CC;
        const u16* w1i   = w1b + (long)i * FCx * Cx;
        const u16* w2i   = w2b + (long)i * Cx * FCx;
        const float* bqkvi = bqkvf + (long)i * C3;

        // fused QKV projection; V-tiles write vt directly (transposed epilogue)
        gemm_bt<128, 128><<<dim3(C3 / 128, BL_ / 128), 256, 0, stream>>>(
            xt, wqkvi, qkv, bqkvi, Cx, Cx, Cx, C3, 0, vt);

        flash_attn<<<dim3(Lx / 64, Bx * Hx), 256, 0, stream>>>(
            qkv, vt, rk + i * 9 * Dx, rv + i * 9 * Dx, ao);

        // O-projection: split-K=2, combine + bias + residual(xt) + LN -> x2
        gemm_sk<128, 128><<<dim3(Cx / 128, BL_ / 128, 2), 256, 0, stream>>>(
            ao, woi, pp, Cx, Cx, Cx / 2);
        combine_ln<2><<<dim3(BL_ / 4), 256, 0, stream>>>(
            pp, bo + i * Cx, xt, x2, l1g + i * Cx, l1b + i * Cx);

        // FFN1 (bias+relu)
        gemm_bt<128, 128><<<dim3(FCx / 128, BL_ / 128), 256, 0, stream>>>(
            x2, w1i, h1, b1 + i * FCx, Cx, Cx, Cx, FCx, 1, nullptr);

        // FFN2: split-K=2, combine + bias + residual(x2) + LN -> xt
        gemm_sk<128, 128><<<dim3(Cx / 128, BL_ / 128, 2), 256, 0, stream>>>(
            h1, w2i, pp, FCx, FCx, FCx / 2);
        combine_ln<2><<<dim3(BL_ / 4), 256, 0, stream>>>(
            pp, b2 + i * Cx, x2, xt, l2g + i * Cx, l2b + i * Cx);
    }

    transpose_k<u16, float><<<dim3(Cx / 32, Lx / 32, Bx), 256, 0, stream>>>(
        xt, out, Cx, Lx, 1, (long)Lx * Cx, 0, (long)Cx * Lx, 0);
}